// Round 1
// baseline (19.542 us; speedup 1.0000x reference)
//
#include <hip/hip_runtime.h>
#include <math.h>

// Cox partial log-likelihood, N=8192.
// loss = -mean_i ( (hazard[i] - log( sum_j exp(hazard[j]) * [time[j]>=time[i]] )) * censor[i] )
//
// Strategy: O(N^2) masked reduction, VALU-bound (~192M lane-ops ~ 2.5us floor).
// Stage time[] and exp(hazard)[] in LDS (64KB). Each wave owns 8 i-values
// (amortize each LDS j-read over 8 accumulators), sweeps all 8192 j via
// conflict-free float4 LDS reads. Deterministic tree reduction, no atomics.

#define COX_N 8192
#define COX_BLOCKS 256
#define COX_TPB 256
#define WAVES_PER_BLOCK (COX_TPB / 64)          // 4
#define I_PER_WAVE 8
#define I_PER_BLOCK (WAVES_PER_BLOCK * I_PER_WAVE) // 32; 256 blocks * 32 = 8192
#define NPARTIAL (COX_BLOCKS * WAVES_PER_BLOCK)    // 1024 wave partials

__global__ __launch_bounds__(COX_TPB) void cox_main(const float* __restrict__ hazard,
                                                    const float* __restrict__ time_,
                                                    const float* __restrict__ censor,
                                                    float* __restrict__ partials) {
    __shared__ __align__(16) float t_lds[COX_N];
    __shared__ __align__(16) float e_lds[COX_N];

    const int t = threadIdx.x;

    // Cooperative load: all 8192 times + exp(hazard) into LDS, float4-vectorized.
    const float4* t4 = reinterpret_cast<const float4*>(time_);
    const float4* h4 = reinterpret_cast<const float4*>(hazard);
    float4* tl4 = reinterpret_cast<float4*>(t_lds);
    float4* el4 = reinterpret_cast<float4*>(e_lds);
    #pragma unroll
    for (int idx = t; idx < COX_N / 4; idx += COX_TPB) {
        float4 tv = t4[idx];
        float4 hv = h4[idx];
        float4 ev;
        ev.x = expf(hv.x);
        ev.y = expf(hv.y);
        ev.z = expf(hv.z);
        ev.w = expf(hv.w);
        tl4[idx] = tv;
        el4[idx] = ev;
    }
    __syncthreads();

    const int lane = t & 63;
    const int wid  = t >> 6;                       // wave id 0..3
    const int iBase = blockIdx.x * I_PER_BLOCK + wid * I_PER_WAVE;

    // 8 i-values per wave (broadcast LDS reads: same addr across wave -> free)
    float ti[I_PER_WAVE];
    #pragma unroll
    for (int ii = 0; ii < I_PER_WAVE; ++ii) ti[ii] = t_lds[iBase + ii];

    float acc[I_PER_WAVE];
    #pragma unroll
    for (int ii = 0; ii < I_PER_WAVE; ++ii) acc[ii] = 0.0f;

    // Sweep all j: lane l covers j = k*256 + 4l (+0..3). Contiguous 1KB/wave
    // per ds_read_b128 pair -> conflict-free.
    #pragma unroll 2
    for (int k = 0; k < COX_N / 256; ++k) {        // 32 iterations
        const int j = (k << 8) + (lane << 2);
        const float4 tj = *reinterpret_cast<const float4*>(t_lds + j);
        const float4 ej = *reinterpret_cast<const float4*>(e_lds + j);
        const float tjv[4] = {tj.x, tj.y, tj.z, tj.w};
        const float ejv[4] = {ej.x, ej.y, ej.z, ej.w};
        #pragma unroll
        for (int c = 0; c < 4; ++c) {
            #pragma unroll
            for (int ii = 0; ii < I_PER_WAVE; ++ii) {
                acc[ii] += (tjv[c] >= ti[ii]) ? ejv[c] : 0.0f;
            }
        }
    }

    // Butterfly reduce each accumulator across the 64-lane wave.
    #pragma unroll
    for (int ii = 0; ii < I_PER_WAVE; ++ii) {
        float r = acc[ii];
        #pragma unroll
        for (int off = 32; off > 0; off >>= 1) r += __shfl_xor(r, off, 64);
        acc[ii] = r;                               // all lanes hold risk_sum
    }

    if (lane == 0) {
        float s = 0.0f;
        #pragma unroll
        for (int ii = 0; ii < I_PER_WAVE; ++ii) {
            const int i = iBase + ii;
            s += (hazard[i] - logf(acc[ii])) * censor[i];
        }
        partials[blockIdx.x * WAVES_PER_BLOCK + wid] = s;
    }
}

__global__ __launch_bounds__(256) void cox_finalize(const float* __restrict__ partials,
                                                    float* __restrict__ out) {
    __shared__ float red[4];
    const int t = threadIdx.x;
    float s = partials[t] + partials[t + 256] + partials[t + 512] + partials[t + 768];
    #pragma unroll
    for (int off = 32; off > 0; off >>= 1) s += __shfl_xor(s, off, 64);
    if ((t & 63) == 0) red[t >> 6] = s;
    __syncthreads();
    if (t == 0) out[0] = -(red[0] + red[1] + red[2] + red[3]) / (float)COX_N;
}

extern "C" void kernel_launch(void* const* d_in, const int* in_sizes, int n_in,
                              void* d_out, int out_size, void* d_ws, size_t ws_size,
                              hipStream_t stream) {
    const float* hazard = (const float*)d_in[0];
    const float* time_  = (const float*)d_in[1];
    const float* censor = (const float*)d_in[2];
    float* out = (float*)d_out;
    float* partials = (float*)d_ws;               // 1024 floats = 4KB

    hipLaunchKernelGGL(cox_main, dim3(COX_BLOCKS), dim3(COX_TPB), 0, stream,
                       hazard, time_, censor, partials);
    hipLaunchKernelGGL(cox_finalize, dim3(1), dim3(256), 0, stream, partials, out);
}

// Round 2
// 16.062 us; speedup vs baseline: 1.2167x; 1.2167x over previous
//
#include <hip/hip_runtime.h>
#include <math.h>

// Cox partial log-likelihood, N=8192.
// loss = -mean_i ( (hazard[i] - log( sum_j exp(hazard[j]) * [time[j]>=time[i]] )) * censor[i] )
//
// R2: occupancy fix. R1 ran 1 wave/SIMD (64KB LDS/block) and sat ~6x off the
// VALU floor (2.56us). Split j 4-ways: 16KB LDS/block -> 4 blocks/CU ->
// 4 waves/SIMD. IPT=8 keeps LDS pipe (~3072 cyc/CU) under VALU (~6144
// cyc/SIMD). Main writes partial risk sums to ws; finalize does log+mean.

#define COX_N    8192
#define COX_TPB  256
#define JSPLIT   4
#define JCHUNK   (COX_N / JSPLIT)            // 2048
#define IPT      8                           // i-values per wave
#define WPB      (COX_TPB / 64)              // 4 waves/block
#define I_PER_BLOCK (WPB * IPT)              // 32
#define ICHUNKS  (COX_N / I_PER_BLOCK)       // 256
// grid = ICHUNKS * JSPLIT = 1024 blocks -> 4 blocks/CU, 16 waves/CU

__global__ __launch_bounds__(COX_TPB, 4) void cox_main(const float* __restrict__ hazard,
                                                       const float* __restrict__ time_,
                                                       float* __restrict__ partials) {
    __shared__ __align__(16) float t_lds[JCHUNK];
    __shared__ __align__(16) float e_lds[JCHUNK];

    const int t  = threadIdx.x;
    const int ic = blockIdx.x & (ICHUNKS - 1);   // i-chunk 0..255
    const int js = blockIdx.x >> 8;              // j-split 0..3
    const int jbase = js * JCHUNK;

    const int lane = t & 63;
    const int wid  = t >> 6;
    const int iBase = ic * I_PER_BLOCK + wid * IPT;

    // i-side times from global (wave-uniform, L2-hot after first blocks).
    float ti[IPT];
    #pragma unroll
    for (int ii = 0; ii < IPT; ++ii) ti[ii] = time_[iBase + ii];

    // Stage this block's j-chunk: 2048 t's + exp(hazard)'s, float4-vectorized.
    const float4* tg = reinterpret_cast<const float4*>(time_ + jbase);
    const float4* hg = reinterpret_cast<const float4*>(hazard + jbase);
    float4* tl4 = reinterpret_cast<float4*>(t_lds);
    float4* el4 = reinterpret_cast<float4*>(e_lds);
    #pragma unroll
    for (int idx = t; idx < JCHUNK / 4; idx += COX_TPB) {   // 2 iterations
        float4 tv = tg[idx];
        float4 hv = hg[idx];
        float4 ev;
        ev.x = expf(hv.x); ev.y = expf(hv.y);
        ev.z = expf(hv.z); ev.w = expf(hv.w);
        tl4[idx] = tv;
        el4[idx] = ev;
    }
    __syncthreads();

    float acc[IPT];
    #pragma unroll
    for (int ii = 0; ii < IPT; ++ii) acc[ii] = 0.0f;

    // Sweep the 2048-j chunk: lane l reads j = k*256 + 4l (+0..3), contiguous
    // 1KB/wave ds_read_b128 -> conflict-free. 8 k-iterations, fully unrolled.
    #pragma unroll
    for (int k = 0; k < JCHUNK / 256; ++k) {
        const int j = (k << 8) + (lane << 2);
        const float4 tj = *reinterpret_cast<const float4*>(t_lds + j);
        const float4 ej = *reinterpret_cast<const float4*>(e_lds + j);
        const float tjv[4] = {tj.x, tj.y, tj.z, tj.w};
        const float ejv[4] = {ej.x, ej.y, ej.z, ej.w};
        #pragma unroll
        for (int c = 0; c < 4; ++c) {
            #pragma unroll
            for (int ii = 0; ii < IPT; ++ii) {
                acc[ii] += (tjv[c] >= ti[ii]) ? ejv[c] : 0.0f;
            }
        }
    }

    // Butterfly-reduce each accumulator across the 64-lane wave.
    #pragma unroll
    for (int ii = 0; ii < IPT; ++ii) {
        float r = acc[ii];
        #pragma unroll
        for (int off = 32; off > 0; off >>= 1) r += __shfl_xor(r, off, 64);
        acc[ii] = r;
    }

    if (lane == 0) {
        #pragma unroll
        for (int ii = 0; ii < IPT; ++ii)
            partials[js * COX_N + iBase + ii] = acc[ii];
    }
}

__global__ __launch_bounds__(1024) void cox_finalize(const float* __restrict__ partials,
                                                     const float* __restrict__ hazard,
                                                     const float* __restrict__ censor,
                                                     float* __restrict__ out) {
    __shared__ float red[16];
    const int t = threadIdx.x;

    const float4* p0 = reinterpret_cast<const float4*>(partials);
    const float4* p1 = reinterpret_cast<const float4*>(partials + COX_N);
    const float4* p2 = reinterpret_cast<const float4*>(partials + 2 * COX_N);
    const float4* p3 = reinterpret_cast<const float4*>(partials + 3 * COX_N);
    const float4* h4 = reinterpret_cast<const float4*>(hazard);
    const float4* c4 = reinterpret_cast<const float4*>(censor);

    float s = 0.0f;
    #pragma unroll
    for (int pass = 0; pass < COX_N / 4 / 1024; ++pass) {   // 2 passes
        const int idx = pass * 1024 + t;                    // float4 index
        float4 a = p0[idx], b = p1[idx], c = p2[idx], d = p3[idx];
        float4 h = h4[idx], cc = c4[idx];
        s += (h.x - logf(a.x + b.x + c.x + d.x)) * cc.x;
        s += (h.y - logf(a.y + b.y + c.y + d.y)) * cc.y;
        s += (h.z - logf(a.z + b.z + c.z + d.z)) * cc.z;
        s += (h.w - logf(a.w + b.w + c.w + d.w)) * cc.w;
    }

    #pragma unroll
    for (int off = 32; off > 0; off >>= 1) s += __shfl_xor(s, off, 64);
    if ((t & 63) == 0) red[t >> 6] = s;
    __syncthreads();
    if (t == 0) {
        float tot = 0.0f;
        #pragma unroll
        for (int w = 0; w < 16; ++w) tot += red[w];
        out[0] = -tot / (float)COX_N;
    }
}

extern "C" void kernel_launch(void* const* d_in, const int* in_sizes, int n_in,
                              void* d_out, int out_size, void* d_ws, size_t ws_size,
                              hipStream_t stream) {
    const float* hazard = (const float*)d_in[0];
    const float* time_  = (const float*)d_in[1];
    const float* censor = (const float*)d_in[2];
    float* out = (float*)d_out;
    float* partials = (float*)d_ws;               // 4 * 8192 floats = 128KB

    hipLaunchKernelGGL(cox_main, dim3(ICHUNKS * JSPLIT), dim3(COX_TPB), 0, stream,
                       hazard, time_, partials);
    hipLaunchKernelGGL(cox_finalize, dim3(1), dim3(1024), 0, stream,
                       partials, hazard, censor, out);
}